// Round 2
// baseline (546.650 us; speedup 1.0000x reference)
//
#include <hip/hip_runtime.h>
#include <hip/hip_bf16.h>

// ---------------------------------------------------------------------------
// MoE dense all-expert forward, MI355X / gfx950.  B=16384, D=H=O=256, E=32.
// Round 6: merged-role waves (spill fix).
//  k0: cvt_w : W1,W2 f32 -> bf16, layout [m][slot s(16)][e(33)][kb(8)] chunks
//      of 512 bf16 (16 rows x 32 k, mfma 16x16x32 A-frag order).
//  k1: moe   : 256 blocks x 1024 thr (16 waves, 4/SIMD). Every wave owns 16
//      h-cols AND 16 out-cols (no crew split -> oacc+hacc = 32 regs total,
//      no spills under the 128-reg budget). Per phase e: fused kb loop does
//      GEMM1(e) from x_s and GEMM2(e-1) from h_s[(e-1)&1], 8 MFMAs per kb
//      between two weight prefetches (depth-4 register rings per stream).
//      One raw s_barrier per phase with lgkmcnt-only drain: weight loads
//      stay in flight across the barrier (no vmcnt(0) drain).
// ---------------------------------------------------------------------------

typedef __attribute__((ext_vector_type(8))) short bf16x8;   // 8 bf16 = 4 VGPRs
typedef __attribute__((ext_vector_type(4))) float f32x4;

__device__ __forceinline__ unsigned short f2bf(float f) {
    unsigned u = __builtin_bit_cast(unsigned, f);
    u += 0x7FFFu + ((u >> 16) & 1u);        // round-to-nearest-even
    return (unsigned short)(u >> 16);
}
__device__ __forceinline__ unsigned pack_bf16x2(float a, float b) {
    return (unsigned)f2bf(a) | ((unsigned)f2bf(b) << 16);
}

// 16B-chunk XOR swizzle for [64 rows][256 elem] bf16 tiles (index in ushorts)
#define LX(r, ch) (((r) << 8) + ((((ch) ^ ((r) & 7))) << 3))

// ------------------- W f32 -> bf16 convert + tile reorder ------------------
// Stream (m, s): m=0 -> W1 rows s*16..s*16+15, m=1 -> W2 rows s*16..; 33
// experts (expert 32 = prefetch-overrun pad, unwritten) x 8 kb-chunks.
// Chunk = 512 bf16 = 1 KB, element (lane, j): row = s*16 + (lane&15),
// k = kb*32 + (lane>>4)*8 + j  — exactly the mfma_16x16x32 A-frag order.
__global__ __launch_bounds__(256) void cvt_w(const float* __restrict__ W1,
                                             const float* __restrict__ W2,
                                             unsigned short* __restrict__ Wr) {
    int T = blockIdx.x * 256 + threadIdx.x;          // 524288 threads
    int lane = T & 63, kb = (T >> 6) & 7, e = (T >> 9) & 31;
    int s = (T >> 14) & 15, m = T >> 18;
    int l15 = lane & 15, quad = lane >> 4;
    const float* src = (m ? W2 : W1) +
                       ((long)e * 256 + s * 16 + l15) * 256 + kb * 32 + quad * 8;
    float4 v0 = ((const float4*)src)[0], v1 = ((const float4*)src)[1];
    uint4 o;
    o.x = pack_bf16x2(v0.x, v0.y); o.y = pack_bf16x2(v0.z, v0.w);
    o.z = pack_bf16x2(v1.x, v1.y); o.w = pack_bf16x2(v1.z, v1.w);
    long U = (((long)(m * 16 + s) * 33 + e) * 8 + kb) * 64 + lane;
    ((uint4*)Wr)[U] = o;
}

// ------------------------------ fused MoE ----------------------------------
// One GEMM1 kb step: consume W1 ring slot, refill 4 chunks ahead, 4 MFMAs.
#define G1STEP(kb) do {                                                        \
    bf16x8 a = r1[(kb) & 3];                                                   \
    r1[(kb) & 3] = *(const bf16x8*)(w1p + (e * 8 + (kb) + 4) * 512);           \
    bf16x8 xb0 = *(const bf16x8*)(&x_s[LX(l15,      (kb) * 4 + quad)]);        \
    bf16x8 xb1 = *(const bf16x8*)(&x_s[LX(16 + l15, (kb) * 4 + quad)]);        \
    bf16x8 xb2 = *(const bf16x8*)(&x_s[LX(32 + l15, (kb) * 4 + quad)]);        \
    bf16x8 xb3 = *(const bf16x8*)(&x_s[LX(48 + l15, (kb) * 4 + quad)]);        \
    __builtin_amdgcn_s_setprio(1);                                             \
    hacc[0] = __builtin_amdgcn_mfma_f32_16x16x32_bf16(a, xb0, hacc[0], 0, 0, 0); \
    hacc[1] = __builtin_amdgcn_mfma_f32_16x16x32_bf16(a, xb1, hacc[1], 0, 0, 0); \
    hacc[2] = __builtin_amdgcn_mfma_f32_16x16x32_bf16(a, xb2, hacc[2], 0, 0, 0); \
    hacc[3] = __builtin_amdgcn_mfma_f32_16x16x32_bf16(a, xb3, hacc[3], 0, 0, 0); \
    __builtin_amdgcn_s_setprio(0);                                             \
} while (0)

// One GEMM2 kb step: consume W2 ring slot, refill, 4 MFMAs from h_s[(e-1)&1].
#define G2STEP(kb) do {                                                        \
    bf16x8 a = r2[(kb) & 3];                                                   \
    r2[(kb) & 3] = *(const bf16x8*)(w2p + (me * 8 + (kb) + 4) * 512);          \
    bf16x8 hb0 = *(const bf16x8*)(&hbr[LX(l15,      (kb) * 4 + quad)]);        \
    bf16x8 hb1 = *(const bf16x8*)(&hbr[LX(16 + l15, (kb) * 4 + quad)]);        \
    bf16x8 hb2 = *(const bf16x8*)(&hbr[LX(32 + l15, (kb) * 4 + quad)]);        \
    bf16x8 hb3 = *(const bf16x8*)(&hbr[LX(48 + l15, (kb) * 4 + quad)]);        \
    __builtin_amdgcn_s_setprio(1);                                             \
    oacc[0] = __builtin_amdgcn_mfma_f32_16x16x32_bf16(a, hb0, oacc[0], 0, 0, 0); \
    oacc[1] = __builtin_amdgcn_mfma_f32_16x16x32_bf16(a, hb1, oacc[1], 0, 0, 0); \
    oacc[2] = __builtin_amdgcn_mfma_f32_16x16x32_bf16(a, hb2, oacc[2], 0, 0, 0); \
    oacc[3] = __builtin_amdgcn_mfma_f32_16x16x32_bf16(a, hb3, oacc[3], 0, 0, 0); \
    __builtin_amdgcn_s_setprio(0);                                             \
} while (0)

__global__ __launch_bounds__(1024, 4) void moe_kernel(
    const float* __restrict__ x,
    const unsigned short* __restrict__ Wr,
    const float* __restrict__ bias1,
    const float* __restrict__ b2,
    const float* __restrict__ Wg,
    const float* __restrict__ bg,
    float* __restrict__ out)
{
    __shared__ __align__(16) unsigned short x_s[64 * 256];      // 32 KB
    __shared__ __align__(16) unsigned short h_s[2][64 * 256];   // 64 KB dbuf
    __shared__ float gws[64 * 33];                              // gate weights

    const int tid  = threadIdx.x;
    const int wv   = tid >> 6, lane = tid & 63;
    const int quad = lane >> 4, l15 = lane & 15;
    const int row0 = blockIdx.x * 64;

    // ---- stage x tile: f32 global -> bf16 LDS (swizzled) ----
#pragma unroll
    for (int c = 0; c < 2; ++c) {
        int chunk = tid + c * 1024;             // 2048 chunks of 8 elems
        int r = chunk >> 5, ch = chunk & 31;
        const float4* s = (const float4*)(x + (long)(row0 + r) * 256 + ch * 8);
        float4 v0 = s[0], v1 = s[1];
        uint4 o;
        o.x = pack_bf16x2(v0.x, v0.y); o.y = pack_bf16x2(v0.z, v0.w);
        o.z = pack_bf16x2(v1.x, v1.y); o.w = pack_bf16x2(v1.z, v1.w);
        *(uint4*)(&x_s[LX(r, ch)]) = o;
    }

    // ---- inline gating: 4 rows per wave, all f32 (matches reference) ----
    {
        const int e32 = lane & 31, half = lane >> 5;
        const float4* wg4 = (const float4*)(Wg + e32 * 256 + half * 128);
        float bgv = bg[e32];
        for (int i = 0; i < 4; ++i) {
            int lr = wv * 4 + i;
            const float4* xr4 = (const float4*)(x + (long)(row0 + lr) * 256 + half * 128);
            float acc = 0.f;
#pragma unroll
            for (int tt = 0; tt < 32; ++tt) {
                float4 w = wg4[tt], xv = xr4[tt];
                acc = fmaf(w.x, xv.x, acc); acc = fmaf(w.y, xv.y, acc);
                acc = fmaf(w.z, xv.z, acc); acc = fmaf(w.w, xv.w, acc);
            }
            acc += __shfl_xor(acc, 32);
            float score = (acc + bgv) / 2.71828182845904523f;   // TEMP = e

            float m = score;
#pragma unroll
            for (int d = 16; d >= 1; d >>= 1) m = fmaxf(m, __shfl_xor(m, d));
            float p = expf(score - m);
            float ps = p;
#pragma unroll
            for (int d = 16; d >= 1; d >>= 1) ps += __shfl_xor(ps, d);
            float prob = p / ps;

            int rank = 0;
#pragma unroll
            for (int j = 0; j < 32; ++j) {
                float pj = __shfl(prob, j);
                rank += (pj > prob || (pj == prob && j < e32)) ? 1 : 0;
            }
            float kept = (rank < 22) ? prob : 0.f;
            float wsum = kept;
#pragma unroll
            for (int d = 16; d >= 1; d >>= 1) wsum += __shfl_xor(wsum, d);
            float weight = kept / (wsum + 1e-8f);

            if (half == 0) gws[lr * 33 + e32] = weight;
        }
    }

    __syncthreads();   // x_s + gws ready

    // ---- weight stream bases + depth-4 register ring preload ----
    const unsigned short* w1p = Wr + (long)wv * 33 * 4096 + lane * 8;
    const unsigned short* w2p = Wr + (long)(16 + wv) * 33 * 4096 + lane * 8;
    bf16x8 r1[4], r2[4];
#pragma unroll
    for (int t = 0; t < 4; ++t) {
        r1[t] = *(const bf16x8*)(w1p + t * 512);
        r2[t] = *(const bf16x8*)(w2p + t * 512);
    }

    // ---- oacc init = sum_e gw * b2 (in-register bias2 combine) ----
    f32x4 oacc[4];
#pragma unroll
    for (int rt = 0; rt < 4; ++rt) {
        f32x4 z = {0.f, 0.f, 0.f, 0.f};
        oacc[rt] = z;
    }
    for (int ee = 0; ee < 32; ++ee) {
        float4 bb = *(const float4*)(b2 + ee * 256 + wv * 16 + quad * 4);
#pragma unroll
        for (int rt = 0; rt < 4; ++rt) {
            float gv = gws[(rt * 16 + l15) * 33 + ee];
            oacc[rt][0] = fmaf(gv, bb.x, oacc[rt][0]);
            oacc[rt][1] = fmaf(gv, bb.y, oacc[rt][1]);
            oacc[rt][2] = fmaf(gv, bb.z, oacc[rt][2]);
            oacc[rt][3] = fmaf(gv, bb.w, oacc[rt][3]);
        }
    }

    // ---- expert pipeline: per phase e, GEMM1(e) + GEMM2(e-1) fused ----
    for (int e = 0; e <= 32; ++e) {
        f32x4 hacc[4];
#pragma unroll
        for (int rt = 0; rt < 4; ++rt) {
            f32x4 z = {0.f, 0.f, 0.f, 0.f};
            hacc[rt] = z;
        }
        const int me = e - 1;
        const unsigned short* hbr = h_s[(e + 1) & 1];   // == h_s[(e-1)&1]

        if (e == 0) {
#pragma unroll
            for (int kb = 0; kb < 8; ++kb) G1STEP(kb);
        } else if (e < 32) {
#pragma unroll
            for (int kb = 0; kb < 8; ++kb) { G1STEP(kb); G2STEP(kb); }
        } else {
#pragma unroll
            for (int kb = 0; kb < 8; ++kb) G2STEP(kb);
        }

        // epilogue: +b1, relu, * gate weight, packed b64 -> h_s[e&1]
        if (e < 32) {
            float4 bv = *(const float4*)(bias1 + e * 256 + wv * 16 + quad * 4);
            unsigned short* hw = h_s[e & 1];
            int ch = wv * 2 + (quad >> 1), off = (quad & 1) * 4;
#pragma unroll
            for (int rt = 0; rt < 4; ++rt) {
                int r = rt * 16 + l15;
                float gw = gws[r * 33 + e];
                float v0 = fmaxf(hacc[rt][0] + bv.x, 0.f) * gw;
                float v1 = fmaxf(hacc[rt][1] + bv.y, 0.f) * gw;
                float v2 = fmaxf(hacc[rt][2] + bv.z, 0.f) * gw;
                float v3 = fmaxf(hacc[rt][3] + bv.w, 0.f) * gw;
                uint2 pk;
                pk.x = pack_bf16x2(v0, v1);
                pk.y = pack_bf16x2(v2, v3);
                *(uint2*)(&hw[(r << 8) + ((ch ^ (r & 7)) << 3) + off]) = pk;
            }
        }

        // barrier with LDS-only drain: weight prefetches stay in flight
        asm volatile("s_waitcnt lgkmcnt(0)" ::: "memory");
        __builtin_amdgcn_s_barrier();
    }

    // ---- final store: out^T frags -> out ----
#pragma unroll
    for (int rt = 0; rt < 4; ++rt)
        *(f32x4*)(out + (long)(row0 + rt * 16 + l15) * 256 +
                  wv * 16 + quad * 4) = oacc[rt];
}

// ------------------------------- launch ------------------------------------
extern "C" void kernel_launch(void* const* d_in, const int* in_sizes, int n_in,
                              void* d_out, int out_size, void* d_ws, size_t ws_size,
                              hipStream_t stream) {
    (void)in_sizes; (void)n_in; (void)out_size; (void)ws_size;
    const float* x  = (const float*)d_in[0];   // [16384,256]
    const float* W1 = (const float*)d_in[1];   // [32,256,256]
    const float* b1 = (const float*)d_in[2];   // [32,256]
    const float* W2 = (const float*)d_in[3];   // [32,256,256]
    const float* b2 = (const float*)d_in[4];   // [32,256]
    const float* Wg = (const float*)d_in[5];   // [32,256]
    const float* bg = (const float*)d_in[6];   // [32]
    float* out = (float*)d_out;                // [16384,256]

    // ws: Wr = 32 streams x 33 experts x 8 KB = 8.45 MB (expert 32 = pad)
    unsigned short* Wr = (unsigned short*)d_ws;

    cvt_w<<<2048, 256, 0, stream>>>(W1, W2, Wr);
    moe_kernel<<<256, 1024, 0, stream>>>(x, Wr, b1, b2, Wg, bg, out);
}